// Round 2
// baseline (884.755 us; speedup 1.0000x reference)
//
#include <hip/hip_runtime.h>
#include <math.h>

// Problem constants (from reference)
#define NSENT 131072
#define NBAGS 8192
#define DIM   690
#define NCLS  53
#define PAIRS 345   // DIM/2 (rows are 8B-aligned: 690*4=2760 % 8 == 0)

// workspace layout
#define COMB_BYTES  (NCLS * DIM * 4)          // 146280 B
#define LOGITS_OFF  153600                    // 150 KB, 256B-aligned
#define WS_NEEDED   (LOGITS_OFF + NSENT * 4)  // 677888 B

// ---------------------------------------------------------------------------
// Kernel 0: comb[q][d] = attention_weight[q][d] * relation_weight[q][d]
// ---------------------------------------------------------------------------
__global__ void comb_kernel(const float* __restrict__ att,
                            const float* __restrict__ rel,
                            float* __restrict__ comb) {
    int i = blockIdx.x * 256 + threadIdx.x;
    if (i < NCLS * DIM) comb[i] = att[i] * rel[i];
}

// ---------------------------------------------------------------------------
// Pass A: logits[i] = dot(x_i, comb[q_i]).  Sentence-parallel, perfectly
// load-balanced, no cross-sentence dependency -> pure streaming of x.
// 8192 waves, each owns a contiguous chunk of 16 sentences, processed 2 at a
// time (two independent dot/reduce chains for ILP + deep load pipelining).
// ---------------------------------------------------------------------------
__global__ __launch_bounds__(256, 8) void logits_kernel(
        const float* __restrict__ x,
        const float* __restrict__ comb,
        const int*   __restrict__ query,
        float*       __restrict__ logits) {
    const int lane = threadIdx.x & 63;
    const int wid  = (blockIdx.x * 256 + threadIdx.x) >> 6;  // 0..8191
    const int i0   = wid * 16;                               // 8192*16 = NSENT

#pragma unroll 1
    for (int i = i0; i < i0 + 16; i += 2) {
        const int q0 = query[i];
        const int q1 = query[i + 1];
        const float2* x0 = (const float2*)(x + (size_t)i * DIM);
        const float2* x1 = (const float2*)(x + (size_t)(i + 1) * DIM);
        const float2* c0 = (const float2*)(comb + (size_t)q0 * DIM);
        const float2* c1 = (const float2*)(comb + (size_t)q1 * DIM);

        float p0 = 0.f, p1 = 0.f;
#pragma unroll
        for (int k = 0; k < 6; ++k) {
            const int p = lane + 64 * k;
            if (p < PAIRS) {
                const float2 a0 = x0[p], b0 = c0[p];
                const float2 a1 = x1[p], b1 = c1[p];
                p0 = fmaf(a0.x, b0.x, fmaf(a0.y, b0.y, p0));
                p1 = fmaf(a1.x, b1.x, fmaf(a1.y, b1.y, p1));
            }
        }
#pragma unroll
        for (int off = 32; off >= 1; off >>= 1) {
            p0 += __shfl_xor(p0, off, 64);
            p1 += __shfl_xor(p1, off, 64);
        }
        if (lane == 0) {
            logits[i]     = p0;
            logits[i + 1] = p1;
        }
    }
}

// ---------------------------------------------------------------------------
// Pass B: one 64-thread block per bag (8192 blocks -> hardware refill
// rebalances the bag-size tail).  Softmax over the bag's logits is
// lane-parallel (ONE shuffle-reduce per bag per phase, not per sentence);
// the weighted-accumulate loop has NO serializing reduction -- its only
// cross-iteration dependency is the per-lane acc FMA, so x-row loads
// pipeline arbitrarily deep.  Epilogue: 53 class dots from register acc.
// ---------------------------------------------------------------------------
__global__ __launch_bounds__(64, 4) void bag_kernel(
        const float* __restrict__ x,
        const float* __restrict__ rel,
        const float* __restrict__ bias,
        const float* __restrict__ logits,
        const int*   __restrict__ scope,
        float*       __restrict__ out) {
    const int b    = blockIdx.x;
    const int lane = threadIdx.x;
    const int start = scope[b];
    const int end   = scope[b + 1];

    // phase 1: bag max (lane-strided)
    float mymax = -INFINITY;
    for (int i = start + lane; i < end; i += 64) mymax = fmaxf(mymax, logits[i]);
#pragma unroll
    for (int off = 32; off >= 1; off >>= 1)
        mymax = fmaxf(mymax, __shfl_xor(mymax, off, 64));

    // phase 2: denominator (logits re-read, L1/L2-hit)
    float mysum = 0.f;
    for (int i = start + lane; i < end; i += 64)
        mysum += __expf(logits[i] - mymax);
#pragma unroll
    for (int off = 32; off >= 1; off >>= 1)
        mysum += __shfl_xor(mysum, off, 64);
    const float invL = 1.f / mysum;   // bags are never empty

    // phase 3: weighted accumulate (streaming; no cross-iteration reduce)
    float2 acc[6];
#pragma unroll
    for (int k = 0; k < 6; ++k) acc[k] = make_float2(0.f, 0.f);

#pragma unroll 2
    for (int i = start; i < end; ++i) {
        const float w = __expf(logits[i] - mymax) * invL;   // uniform scalar
        const float2* xrow = (const float2*)(x + (size_t)i * DIM);
#pragma unroll
        for (int k = 0; k < 6; ++k) {
            const int p = lane + 64 * k;
            if (p < PAIRS) {
                const float2 xv = xrow[p];
                acc[k].x = fmaf(w, xv.x, acc[k].x);
                acc[k].y = fmaf(w, xv.y, acc[k].y);
            }
        }
    }

    // ---- epilogue: out[b][c] = dot(acc, rel[c]) + bias[c] ----
    float res = (lane < NCLS) ? bias[lane] : 0.f;

#pragma unroll 1
    for (int c = 0; c < NCLS - 1; c += 2) {
        const float2* r0 = (const float2*)(rel + (size_t)c * DIM);
        const float2* r1 = (const float2*)(rel + (size_t)(c + 1) * DIM);
        float p0 = 0.f, p1 = 0.f;
#pragma unroll
        for (int k = 0; k < 6; ++k) {
            const int p = lane + 64 * k;
            if (p < PAIRS) {
                const float2 v0 = r0[p];
                const float2 v1 = r1[p];
                p0 = fmaf(v0.x, acc[k].x, p0);
                p0 = fmaf(v0.y, acc[k].y, p0);
                p1 = fmaf(v1.x, acc[k].x, p1);
                p1 = fmaf(v1.y, acc[k].y, p1);
            }
        }
#pragma unroll
        for (int off = 32; off >= 1; off >>= 1) {
            p0 += __shfl_xor(p0, off, 64);
            p1 += __shfl_xor(p1, off, 64);
        }
        if (lane == c)     res += p0;
        if (lane == c + 1) res += p1;
    }
    {   // final odd class c = 52
        const int c = NCLS - 1;
        const float2* r0 = (const float2*)(rel + (size_t)c * DIM);
        float p0 = 0.f;
#pragma unroll
        for (int k = 0; k < 6; ++k) {
            const int p = lane + 64 * k;
            if (p < PAIRS) {
                const float2 v0 = r0[p];
                p0 = fmaf(v0.x, acc[k].x, p0);
                p0 = fmaf(v0.y, acc[k].y, p0);
            }
        }
#pragma unroll
        for (int off = 32; off >= 1; off >>= 1)
            p0 += __shfl_xor(p0, off, 64);
        if (lane == c) res += p0;
    }

    if (lane < NCLS) out[(size_t)b * NCLS + lane] = res;   // coalesced 212B
}

// ---------------------------------------------------------------------------
// Fallback (workspace too small): round-1 fused kernel, verified correct.
// ---------------------------------------------------------------------------
template <bool USE_COMB>
__global__ __launch_bounds__(256, 8) void bag_attn_wave_kernel(
        const float* __restrict__ x,
        const float* __restrict__ rel,
        const float* __restrict__ att,
        const float* __restrict__ bias,
        const int*   __restrict__ query,
        const int*   __restrict__ scope,
        const float* __restrict__ comb,
        float*       __restrict__ out) {
    const int tid  = threadIdx.x;
    const int wave = tid >> 6;
    const int lane = tid & 63;
    const int b    = blockIdx.x * 4 + wave;

    const int start = scope[b];
    const int end   = scope[b + 1];

    float2 acc[6];
#pragma unroll
    for (int k = 0; k < 6; ++k) acc[k] = make_float2(0.f, 0.f);
    float m = -INFINITY;
    float l = 0.f;

    for (int i = start; i < end; ++i) {
        const float2* xrow = (const float2*)(x + (size_t)i * DIM);
        const int q = query[i];

        float2 xv[6];
        float partial = 0.f;
        if (USE_COMB) {
            const float2* crow = (const float2*)(comb + (size_t)q * DIM);
#pragma unroll
            for (int k = 0; k < 6; ++k) {
                const int p = lane + 64 * k;
                if (p < PAIRS) {
                    xv[k] = xrow[p];
                    const float2 cv = crow[p];
                    partial = fmaf(xv[k].x, cv.x, partial);
                    partial = fmaf(xv[k].y, cv.y, partial);
                } else xv[k] = make_float2(0.f, 0.f);
            }
        } else {
            const float2* rrow = (const float2*)(rel + (size_t)q * DIM);
            const float2* arow = (const float2*)(att + (size_t)q * DIM);
#pragma unroll
            for (int k = 0; k < 6; ++k) {
                const int p = lane + 64 * k;
                if (p < PAIRS) {
                    xv[k] = xrow[p];
                    const float2 rv = rrow[p];
                    const float2 av = arow[p];
                    partial = fmaf(xv[k].x, rv.x * av.x, partial);
                    partial = fmaf(xv[k].y, rv.y * av.y, partial);
                } else xv[k] = make_float2(0.f, 0.f);
            }
        }
#pragma unroll
        for (int off = 32; off >= 1; off >>= 1)
            partial += __shfl_xor(partial, off, 64);

        const float d = partial - m;
        if (d <= 8.0f) {
            const float e = __expf(d);
#pragma unroll
            for (int k = 0; k < 6; ++k) {
                acc[k].x = fmaf(e, xv[k].x, acc[k].x);
                acc[k].y = fmaf(e, xv[k].y, acc[k].y);
            }
            l += e;
        } else {
            const float r = __expf(-d);
#pragma unroll
            for (int k = 0; k < 6; ++k) {
                acc[k].x = fmaf(acc[k].x, r, xv[k].x);
                acc[k].y = fmaf(acc[k].y, r, xv[k].y);
            }
            l = fmaf(l, r, 1.f);
            m = partial;
        }
    }

    const float inv = 1.f / l;
    float res = (lane < NCLS) ? bias[lane] : 0.f;
#pragma unroll 1
    for (int c = 0; c < NCLS - 1; c += 2) {
        const float2* r0 = (const float2*)(rel + (size_t)c * DIM);
        const float2* r1 = (const float2*)(rel + (size_t)(c + 1) * DIM);
        float p0 = 0.f, p1 = 0.f;
#pragma unroll
        for (int k = 0; k < 6; ++k) {
            const int p = lane + 64 * k;
            if (p < PAIRS) {
                const float2 v0 = r0[p];
                const float2 v1 = r1[p];
                p0 = fmaf(v0.x, acc[k].x, p0);
                p0 = fmaf(v0.y, acc[k].y, p0);
                p1 = fmaf(v1.x, acc[k].x, p1);
                p1 = fmaf(v1.y, acc[k].y, p1);
            }
        }
#pragma unroll
        for (int off = 32; off >= 1; off >>= 1) {
            p0 += __shfl_xor(p0, off, 64);
            p1 += __shfl_xor(p1, off, 64);
        }
        if (lane == c)     res = fmaf(p0, inv, res);
        if (lane == c + 1) res = fmaf(p1, inv, res);
    }
    {
        const int c = NCLS - 1;
        const float2* r0 = (const float2*)(rel + (size_t)c * DIM);
        float p0 = 0.f;
#pragma unroll
        for (int k = 0; k < 6; ++k) {
            const int p = lane + 64 * k;
            if (p < PAIRS) {
                const float2 v0 = r0[p];
                p0 = fmaf(v0.x, acc[k].x, p0);
                p0 = fmaf(v0.y, acc[k].y, p0);
            }
        }
#pragma unroll
        for (int off = 32; off >= 1; off >>= 1)
            p0 += __shfl_xor(p0, off, 64);
        if (lane == c) res = fmaf(p0, inv, res);
    }
    if (lane < NCLS) out[(size_t)b * NCLS + lane] = res;
}

extern "C" void kernel_launch(void* const* d_in, const int* in_sizes, int n_in,
                              void* d_out, int out_size, void* d_ws, size_t ws_size,
                              hipStream_t stream) {
    const float* x     = (const float*)d_in[0];   // [131072, 690]
    const float* rel   = (const float*)d_in[1];   // [53, 690]
    const float* att   = (const float*)d_in[2];   // [53, 690]
    const float* bias  = (const float*)d_in[3];   // [53]
    const int*   query = (const int*)d_in[4];     // [131072]
    const int*   scope = (const int*)d_in[5];     // [8193]
    float*       out   = (float*)d_out;           // [8192, 53]

    if (ws_size >= (size_t)WS_NEEDED) {
        float* comb   = (float*)d_ws;
        float* logits = (float*)((char*)d_ws + LOGITS_OFF);
        comb_kernel<<<(NCLS * DIM + 255) / 256, 256, 0, stream>>>(att, rel, comb);
        logits_kernel<<<NSENT / (16 * 4), 256, 0, stream>>>(x, comb, query, logits);
        bag_kernel<<<NBAGS, 64, 0, stream>>>(x, rel, bias, logits, scope, out);
    } else if (ws_size >= (size_t)COMB_BYTES) {
        float* comb = (float*)d_ws;
        comb_kernel<<<(NCLS * DIM + 255) / 256, 256, 0, stream>>>(att, rel, comb);
        bag_attn_wave_kernel<true><<<NBAGS / 4, 256, 0, stream>>>(
            x, rel, att, bias, query, scope, comb, out);
    } else {
        bag_attn_wave_kernel<false><<<NBAGS / 4, 256, 0, stream>>>(
            x, rel, att, bias, query, scope, nullptr, out);
    }
}

// Round 3
// 687.670 us; speedup vs baseline: 1.2866x; 1.2866x over previous
//
#include <hip/hip_runtime.h>
#include <math.h>

// Problem constants (from reference)
#define NSENT 131072
#define NBAGS 8192
#define DIM   690
#define NCLS  53
#define PAIRS 345   // DIM/2 (rows are 8B-aligned: 690*4=2760 % 8 == 0)
#define MAXS  512   // max sentences per in-LDS chunk (mean bag = 16)

#define COMB_BYTES  (NCLS * DIM * 4)          // 146280 B

// ---------------------------------------------------------------------------
// Kernel 0: comb[q][d] = attention_weight[q][d] * relation_weight[q][d]
// 53*690 = 36570 floats -> tiny, L2-resident table for the main kernel.
// ---------------------------------------------------------------------------
__global__ void comb_kernel(const float* __restrict__ att,
                            const float* __restrict__ rel,
                            float* __restrict__ comb) {
    int i = blockIdx.x * 256 + threadIdx.x;
    if (i < NCLS * DIM) comb[i] = att[i] * rel[i];
}

// ---------------------------------------------------------------------------
// Main kernel: ONE WAVE PER BAG, 4 bags per 256-thread block, no barriers.
// Per bag (in chunks of <=MAXS sentences, one chunk in practice):
//   A : logit[i] = dot(x_i, comb[q_i]), 2 sentences in flight (independent
//       chains -> fully pipelineable, unlike the fused-softmax chain of R1);
//       lane 0 parks logits in wave-private LDS.
//   A2: chunk max via ONE lane-parallel shuffle-reduce (not per sentence).
//   A3: w[i] = exp(logit-M) back into LDS + ONE sum-reduce -> l.
//   B : acc += w * x_i  -- re-reads x rows that this block streamed moments
//       ago (L2/L3 hit, NOT HBM: x crosses HBM once), 12 independent
//       per-lane FMA chains, loads pipeline deep.
// Epilogue: out[b][c] = dot(acc, rel[c])/l + bias[c], 2 classes per iter,
// coalesced 212 B store.
// __launch_bounds__(256,4): 128 VGPRs for load-pipelining depth (R1's
// mistake was forcing 8 waves -> 32 VGPRs -> no outstanding loads).
// ---------------------------------------------------------------------------
template <bool USE_COMB>
__global__ __launch_bounds__(256, 4) void bag_fused_kernel(
        const float* __restrict__ x,
        const float* __restrict__ rel,
        const float* __restrict__ att,
        const float* __restrict__ bias,
        const int*   __restrict__ query,
        const int*   __restrict__ scope,
        const float* __restrict__ comb,
        float*       __restrict__ out) {
    const int tid  = threadIdx.x;
    const int wave = tid >> 6;
    const int lane = tid & 63;
    const int b    = blockIdx.x * 4 + wave;   // one bag per wave

    __shared__ float s_lgt[4][MAXS];          // 8 KiB, wave-private rows
    float* lgt = s_lgt[wave];

    const int start = scope[b];
    const int end   = scope[b + 1];

    float2 acc[6];
#pragma unroll
    for (int k = 0; k < 6; ++k) acc[k] = make_float2(0.f, 0.f);
    float m = -INFINITY;
    float l = 0.f;

    for (int cs = start; cs < end; cs += MAXS) {
        const int ce = (end < cs + MAXS) ? end : (cs + MAXS);
        const int n  = ce - cs;

        // ---- phase A: logits -> LDS (no cross-sentence dependency) ----
        int i = cs;
        for (; i + 1 < ce; i += 2) {
            const int q0 = query[i];
            const int q1 = query[i + 1];
            const float2* x0 = (const float2*)(x + (size_t)i * DIM);
            const float2* x1 = (const float2*)(x + (size_t)(i + 1) * DIM);
            float p0 = 0.f, p1 = 0.f;
            if (USE_COMB) {
                const float2* c0 = (const float2*)(comb + (size_t)q0 * DIM);
                const float2* c1 = (const float2*)(comb + (size_t)q1 * DIM);
#pragma unroll
                for (int k = 0; k < 6; ++k) {
                    const int p = lane + 64 * k;
                    if (p < PAIRS) {
                        const float2 a0 = x0[p], b0 = c0[p];
                        const float2 a1 = x1[p], b1 = c1[p];
                        p0 = fmaf(a0.x, b0.x, fmaf(a0.y, b0.y, p0));
                        p1 = fmaf(a1.x, b1.x, fmaf(a1.y, b1.y, p1));
                    }
                }
            } else {
                const float2* r0 = (const float2*)(rel + (size_t)q0 * DIM);
                const float2* a0r = (const float2*)(att + (size_t)q0 * DIM);
                const float2* r1 = (const float2*)(rel + (size_t)q1 * DIM);
                const float2* a1r = (const float2*)(att + (size_t)q1 * DIM);
#pragma unroll
                for (int k = 0; k < 6; ++k) {
                    const int p = lane + 64 * k;
                    if (p < PAIRS) {
                        const float2 a0 = x0[p], rv0 = r0[p], av0 = a0r[p];
                        const float2 a1 = x1[p], rv1 = r1[p], av1 = a1r[p];
                        p0 = fmaf(a0.x, rv0.x * av0.x, fmaf(a0.y, rv0.y * av0.y, p0));
                        p1 = fmaf(a1.x, rv1.x * av1.x, fmaf(a1.y, rv1.y * av1.y, p1));
                    }
                }
            }
#pragma unroll
            for (int off = 32; off >= 1; off >>= 1) {
                p0 += __shfl_xor(p0, off, 64);
                p1 += __shfl_xor(p1, off, 64);
            }
            if (lane == 0) {
                lgt[i - cs]     = p0;
                lgt[i - cs + 1] = p1;
            }
        }
        if (i < ce) {   // odd tail sentence
            const int q0 = query[i];
            const float2* x0 = (const float2*)(x + (size_t)i * DIM);
            float p0 = 0.f;
            if (USE_COMB) {
                const float2* c0 = (const float2*)(comb + (size_t)q0 * DIM);
#pragma unroll
                for (int k = 0; k < 6; ++k) {
                    const int p = lane + 64 * k;
                    if (p < PAIRS) {
                        const float2 a0 = x0[p], b0 = c0[p];
                        p0 = fmaf(a0.x, b0.x, fmaf(a0.y, b0.y, p0));
                    }
                }
            } else {
                const float2* r0 = (const float2*)(rel + (size_t)q0 * DIM);
                const float2* a0r = (const float2*)(att + (size_t)q0 * DIM);
#pragma unroll
                for (int k = 0; k < 6; ++k) {
                    const int p = lane + 64 * k;
                    if (p < PAIRS) {
                        const float2 a0 = x0[p], rv0 = r0[p], av0 = a0r[p];
                        p0 = fmaf(a0.x, rv0.x * av0.x, fmaf(a0.y, rv0.y * av0.y, p0));
                    }
                }
            }
#pragma unroll
            for (int off = 32; off >= 1; off >>= 1)
                p0 += __shfl_xor(p0, off, 64);
            if (lane == 0) lgt[i - cs] = p0;
        }

        // ---- phase A2: chunk max (ONE reduce per chunk) ----
        float cm = -INFINITY;
        for (int j = lane; j < n; j += 64) cm = fmaxf(cm, lgt[j]);
#pragma unroll
        for (int off = 32; off >= 1; off >>= 1)
            cm = fmaxf(cm, __shfl_xor(cm, off, 64));

        // flash-merge with previous chunks (first chunk: r = exp(-inf) = 0)
        const float Mn = fmaxf(m, cm);
        const float r  = __expf(m - Mn);
        l *= r;
#pragma unroll
        for (int k = 0; k < 6; ++k) {
            acc[k].x *= r;
            acc[k].y *= r;
        }
        m = Mn;

        // ---- phase A3: weights into LDS + denominator ----
        float ps = 0.f;
        for (int j = lane; j < n; j += 64) {
            const float w = __expf(lgt[j] - Mn);
            lgt[j] = w;
            ps += w;
        }
#pragma unroll
        for (int off = 32; off >= 1; off >>= 1)
            ps += __shfl_xor(ps, off, 64);
        l += ps;

        // ---- phase B: weighted accumulate (rows are L2/L3-warm) ----
#pragma unroll 2
        for (int i2 = cs; i2 < ce; ++i2) {
            const float w = lgt[i2 - cs];          // LDS broadcast
            const float2* xr = (const float2*)(x + (size_t)i2 * DIM);
#pragma unroll
            for (int k = 0; k < 6; ++k) {
                const int p = lane + 64 * k;
                if (p < PAIRS) {
                    const float2 xv = xr[p];
                    acc[k].x = fmaf(w, xv.x, acc[k].x);
                    acc[k].y = fmaf(w, xv.y, acc[k].y);
                }
            }
        }
    }

    // ---- epilogue: out[b][c] = dot(acc, rel[c])/l + bias[c] ----
    const float inv = 1.f / l;                     // bags never empty
    float res = (lane < NCLS) ? bias[lane] : 0.f;

#pragma unroll 1
    for (int c = 0; c < NCLS - 1; c += 2) {
        const float2* r0 = (const float2*)(rel + (size_t)c * DIM);
        const float2* r1 = (const float2*)(rel + (size_t)(c + 1) * DIM);
        float p0 = 0.f, p1 = 0.f;
#pragma unroll
        for (int k = 0; k < 6; ++k) {
            const int p = lane + 64 * k;
            if (p < PAIRS) {
                const float2 v0 = r0[p];
                const float2 v1 = r1[p];
                p0 = fmaf(v0.x, acc[k].x, p0);
                p0 = fmaf(v0.y, acc[k].y, p0);
                p1 = fmaf(v1.x, acc[k].x, p1);
                p1 = fmaf(v1.y, acc[k].y, p1);
            }
        }
#pragma unroll
        for (int off = 32; off >= 1; off >>= 1) {
            p0 += __shfl_xor(p0, off, 64);
            p1 += __shfl_xor(p1, off, 64);
        }
        if (lane == c)     res = fmaf(p0, inv, res);
        if (lane == c + 1) res = fmaf(p1, inv, res);
    }
    {   // final odd class c = 52
        const int c = NCLS - 1;
        const float2* r0 = (const float2*)(rel + (size_t)c * DIM);
        float p0 = 0.f;
#pragma unroll
        for (int k = 0; k < 6; ++k) {
            const int p = lane + 64 * k;
            if (p < PAIRS) {
                const float2 v0 = r0[p];
                p0 = fmaf(v0.x, acc[k].x, p0);
                p0 = fmaf(v0.y, acc[k].y, p0);
            }
        }
#pragma unroll
        for (int off = 32; off >= 1; off >>= 1)
            p0 += __shfl_xor(p0, off, 64);
        if (lane == c) res = fmaf(p0, inv, res);
    }

    if (lane < NCLS) out[(size_t)b * NCLS + lane] = res;   // coalesced 212 B
}

extern "C" void kernel_launch(void* const* d_in, const int* in_sizes, int n_in,
                              void* d_out, int out_size, void* d_ws, size_t ws_size,
                              hipStream_t stream) {
    const float* x     = (const float*)d_in[0];   // [131072, 690]
    const float* rel   = (const float*)d_in[1];   // [53, 690]
    const float* att   = (const float*)d_in[2];   // [53, 690]
    const float* bias  = (const float*)d_in[3];   // [53]
    const int*   query = (const int*)d_in[4];     // [131072]
    const int*   scope = (const int*)d_in[5];     // [8193]
    float*       out   = (float*)d_out;           // [8192, 53]

    if (ws_size >= (size_t)COMB_BYTES) {
        float* comb = (float*)d_ws;
        comb_kernel<<<(NCLS * DIM + 255) / 256, 256, 0, stream>>>(att, rel, comb);
        bag_fused_kernel<true><<<NBAGS / 4, 256, 0, stream>>>(
            x, rel, att, bias, query, scope, comb, out);
    } else {
        bag_fused_kernel<false><<<NBAGS / 4, 256, 0, stream>>>(
            x, rel, att, bias, query, scope, nullptr, out);
    }
}

// Round 4
// 595.171 us; speedup vs baseline: 1.4866x; 1.1554x over previous
//
#include <hip/hip_runtime.h>
#include <math.h>

// Problem constants (from reference)
#define NSENT 131072
#define NBAGS 8192
#define DIM   690
#define NCLS  53
#define PAIRS 345   // DIM/2 (rows are 8B-aligned: 690*4=2760 % 8 == 0)

#define COMB_BYTES  (NCLS * DIM * 4)          // 146280 B

// ---------------------------------------------------------------------------
// Kernel 0: comb[q][d] = attention_weight[q][d] * relation_weight[q][d]
// 53*690 = 36570 floats -> tiny, L2-resident table for the main kernel.
// ---------------------------------------------------------------------------
__global__ void comb_kernel(const float* __restrict__ att,
                            const float* __restrict__ rel,
                            float* __restrict__ comb) {
    int i = blockIdx.x * 256 + threadIdx.x;
    if (i < NCLS * DIM) comb[i] = att[i] * rel[i];
}

// ---------------------------------------------------------------------------
// Main kernel (R0 structure + R1 math + pair ILP):
//   - ONE BLOCK PER BAG, 4 waves/bag. 8192 blocks = 32 blocks/CU queued ->
//     hardware refill rebalances the bag-size tail (R3's 1-wave-per-bag had
//     zero refill pool and drained at 27% occupancy).
//   - x is read from HBM exactly ONCE, rows held in registers (R3's split
//     re-read went to HBM: FETCH 339 MB vs 179 MB here).
//   - Each wave processes sentence PAIRS (i, i+1), stride 8: 24 independent
//     row loads + two interleaved shuffle-reduce chains in flight.
//   - Defer-max online softmax (wave-uniform branch, THR=8, validated R1):
//     common path = 1 __expf + 12 FMA per sentence; no rescale, no 2nd exp.
//   - Merge via LDS (2 barriers), bag-repre scaled by 1/L into registers,
//     2-class-ILP epilogue.
// ---------------------------------------------------------------------------
template <bool USE_COMB>
__global__ __launch_bounds__(256, 5) void bag_attn4_kernel(
        const float* __restrict__ x,
        const float* __restrict__ rel,
        const float* __restrict__ att,
        const float* __restrict__ bias,
        const int*   __restrict__ query,
        const int*   __restrict__ scope,
        const float* __restrict__ comb,
        float*       __restrict__ out) {
    const int tid  = threadIdx.x;
    const int wave = tid >> 6;
    const int lane = tid & 63;
    const int b    = blockIdx.x;

    const int start = scope[b];
    const int end   = scope[b + 1];

    float2 acc[6];
#pragma unroll
    for (int k = 0; k < 6; ++k) acc[k] = make_float2(0.f, 0.f);
    float m = -INFINITY;
    float l = 0.f;

    // ---- main loop: pairs (i, i+1) per wave, stride 8 across 4 waves ----
    for (int i = start + 2 * wave; i < end; i += 8) {
        const bool two = (i + 1 < end);
        const int  i1  = two ? i + 1 : i;       // valid row either way
        const int  q0  = query[i];
        const int  q1  = query[i1];
        const float2* xr0 = (const float2*)(x + (size_t)i  * DIM);
        const float2* xr1 = (const float2*)(x + (size_t)i1 * DIM);

        float2 xv0[6], xv1[6];
        float p0 = 0.f, p1 = 0.f;
        if (USE_COMB) {
            const float2* c0 = (const float2*)(comb + (size_t)q0 * DIM);
            const float2* c1 = (const float2*)(comb + (size_t)q1 * DIM);
#pragma unroll
            for (int k = 0; k < 6; ++k) {
                const int p = lane + 64 * k;
                if (p < PAIRS) {
                    xv0[k] = xr0[p];
                    xv1[k] = xr1[p];
                    const float2 cv0 = c0[p];
                    const float2 cv1 = c1[p];
                    p0 = fmaf(xv0[k].x, cv0.x, fmaf(xv0[k].y, cv0.y, p0));
                    p1 = fmaf(xv1[k].x, cv1.x, fmaf(xv1[k].y, cv1.y, p1));
                } else {
                    xv0[k] = make_float2(0.f, 0.f);
                    xv1[k] = make_float2(0.f, 0.f);
                }
            }
        } else {
            const float2* r0 = (const float2*)(rel + (size_t)q0 * DIM);
            const float2* a0 = (const float2*)(att + (size_t)q0 * DIM);
            const float2* r1 = (const float2*)(rel + (size_t)q1 * DIM);
            const float2* a1 = (const float2*)(att + (size_t)q1 * DIM);
#pragma unroll
            for (int k = 0; k < 6; ++k) {
                const int p = lane + 64 * k;
                if (p < PAIRS) {
                    xv0[k] = xr0[p];
                    xv1[k] = xr1[p];
                    const float2 rv0 = r0[p], av0 = a0[p];
                    const float2 rv1 = r1[p], av1 = a1[p];
                    p0 = fmaf(xv0[k].x, rv0.x * av0.x, fmaf(xv0[k].y, rv0.y * av0.y, p0));
                    p1 = fmaf(xv1[k].x, rv1.x * av1.x, fmaf(xv1[k].y, rv1.y * av1.y, p1));
                } else {
                    xv0[k] = make_float2(0.f, 0.f);
                    xv1[k] = make_float2(0.f, 0.f);
                }
            }
        }

        // dual interleaved wave-wide reduce (logits broadcast to all lanes)
#pragma unroll
        for (int off = 32; off >= 1; off >>= 1) {
            p0 += __shfl_xor(p0, off, 64);
            p1 += __shfl_xor(p1, off, 64);
        }

        if (two) {
            const float d0 = p0 - m;
            const float d1 = p1 - m;
            if (d0 <= 8.0f && d1 <= 8.0f) {          // common, wave-uniform
                const float e0 = __expf(d0);
                const float e1 = __expf(d1);
#pragma unroll
                for (int k = 0; k < 6; ++k) {
                    acc[k].x = fmaf(e0, xv0[k].x, fmaf(e1, xv1[k].x, acc[k].x));
                    acc[k].y = fmaf(e0, xv0[k].y, fmaf(e1, xv1[k].y, acc[k].y));
                }
                l += e0 + e1;
            } else {                                  // rare: rescale merge
                const float mn = fmaxf(m, fmaxf(p0, p1));
                const float r  = __expf(m - mn);      // first iter: exp(-inf)=0
                const float e0 = __expf(p0 - mn);
                const float e1 = __expf(p1 - mn);
#pragma unroll
                for (int k = 0; k < 6; ++k) {
                    acc[k].x = fmaf(acc[k].x, r, fmaf(e0, xv0[k].x, e1 * xv1[k].x));
                    acc[k].y = fmaf(acc[k].y, r, fmaf(e0, xv0[k].y, e1 * xv1[k].y));
                }
                l = fmaf(l, r, e0 + e1);
                m = mn;
            }
        } else {                                      // single tail sentence
            const float d0 = p0 - m;
            if (d0 <= 8.0f) {
                const float e0 = __expf(d0);
#pragma unroll
                for (int k = 0; k < 6; ++k) {
                    acc[k].x = fmaf(e0, xv0[k].x, acc[k].x);
                    acc[k].y = fmaf(e0, xv0[k].y, acc[k].y);
                }
                l += e0;
            } else {
                const float mn = fmaxf(m, p0);
                const float r  = __expf(m - mn);
                const float e0 = __expf(p0 - mn);
#pragma unroll
                for (int k = 0; k < 6; ++k) {
                    acc[k].x = fmaf(acc[k].x, r, e0 * xv0[k].x);
                    acc[k].y = fmaf(acc[k].y, r, e0 * xv0[k].y);
                }
                l = fmaf(l, r, e0);
                m = mn;
            }
        }
    }

    // ---- merge the 4 waves' (m, l, acc) via LDS (2 barriers) ----
    __shared__ float  s_m[4];
    __shared__ float  s_l[4];
    __shared__ float2 s_acc[4][PAIRS];   // 4*345*8 = 11040 B

    if (lane == 0) { s_m[wave] = m; s_l[wave] = l; }
    __syncthreads();

    const float M = fmaxf(fmaxf(s_m[0], s_m[1]), fmaxf(s_m[2], s_m[3]));
    float Ltot = 0.f;
#pragma unroll
    for (int w = 0; w < 4; ++w) {
        const float lw = s_l[w];
        Ltot += (lw > 0.f) ? lw * __expf(s_m[w] - M) : 0.f;
    }
    const float factor = (l > 0.f) ? __expf(m - M) : 0.f;
#pragma unroll
    for (int k = 0; k < 6; ++k) {
        const int p = lane + 64 * k;
        if (p < PAIRS)
            s_acc[wave][p] = make_float2(acc[k].x * factor, acc[k].y * factor);
    }
    __syncthreads();

    // merged bag representation, pre-scaled by 1/L, in registers
    const float inv = 1.f / Ltot;        // bags never empty -> Ltot > 0
    float2 am[6];
#pragma unroll
    for (int k = 0; k < 6; ++k) {
        const int p = lane + 64 * k;
        if (p < PAIRS) {
            const float2 a0 = s_acc[0][p], a1 = s_acc[1][p];
            const float2 a2 = s_acc[2][p], a3 = s_acc[3][p];
            am[k] = make_float2(((a0.x + a1.x) + (a2.x + a3.x)) * inv,
                                ((a0.y + a1.y) + (a2.y + a3.y)) * inv);
        } else {
            am[k] = make_float2(0.f, 0.f);
        }
    }

    // ---- epilogue: out[b][c] = dot(repre, rel[c]) + bias[c], 2-class ILP --
#pragma unroll 1
    for (int c0 = wave; c0 < NCLS; c0 += 8) {
        const int  c1 = c0 + 4;
        const bool h2 = (c1 < NCLS);
        const float2* r0 = (const float2*)(rel + (size_t)c0 * DIM);
        const float2* r1 = (const float2*)(rel + (size_t)(h2 ? c1 : c0) * DIM);
        float p0 = 0.f, p1 = 0.f;
#pragma unroll
        for (int k = 0; k < 6; ++k) {
            const int p = lane + 64 * k;
            if (p < PAIRS) {
                const float2 v0 = r0[p];
                const float2 v1 = r1[p];
                p0 = fmaf(v0.x, am[k].x, fmaf(v0.y, am[k].y, p0));
                p1 = fmaf(v1.x, am[k].x, fmaf(v1.y, am[k].y, p1));
            }
        }
#pragma unroll
        for (int off = 32; off >= 1; off >>= 1) {
            p0 += __shfl_xor(p0, off, 64);
            p1 += __shfl_xor(p1, off, 64);
        }
        if (lane == 0) {
            out[(size_t)b * NCLS + c0] = p0 + bias[c0];
            if (h2) out[(size_t)b * NCLS + c1] = p1 + bias[c1];
        }
    }
}

extern "C" void kernel_launch(void* const* d_in, const int* in_sizes, int n_in,
                              void* d_out, int out_size, void* d_ws, size_t ws_size,
                              hipStream_t stream) {
    const float* x     = (const float*)d_in[0];   // [131072, 690]
    const float* rel   = (const float*)d_in[1];   // [53, 690]
    const float* att   = (const float*)d_in[2];   // [53, 690]
    const float* bias  = (const float*)d_in[3];   // [53]
    const int*   query = (const int*)d_in[4];     // [131072]
    const int*   scope = (const int*)d_in[5];     // [8193]
    float*       out   = (float*)d_out;           // [8192, 53]

    if (ws_size >= (size_t)COMB_BYTES) {
        float* comb = (float*)d_ws;
        comb_kernel<<<(NCLS * DIM + 255) / 256, 256, 0, stream>>>(att, rel, comb);
        bag_attn4_kernel<true><<<NBAGS, 256, 0, stream>>>(
            x, rel, att, bias, query, scope, comb, out);
    } else {
        bag_attn4_kernel<false><<<NBAGS, 256, 0, stream>>>(
            x, rel, att, bias, query, scope, nullptr, out);
    }
}